// Round 1
// baseline (491.909 us; speedup 1.0000x reference)
//
#include <hip/hip_runtime.h>

#define NP   4096      // patches
#define DD   768       // embed dim
#define HD   64
#define WD   64
#define KTOP 100
#define BIGL 4097      // N+1

// ---------------- kernel 0: zero counts ----------------
__global__ void k_zero(int* __restrict__ p, int n) {
    int i = blockIdx.x * 256 + threadIdx.x;
    if (i < n) p[i] = 0;
}

// ---------------- kernel 1: per-column nonneg counts of sim = A*A^T ----------------
// Upper-triangular 64x64 tile grid (2080 blocks). fp32, 64x64 tile, 4x4 micro-tile.
#define BK 16
__global__ __launch_bounds__(256) void k_count(const float* __restrict__ A,
                                               int* __restrict__ counts) {
    __shared__ float As[BK][64];
    __shared__ float Bs[BK][64];
    __shared__ int colc[64];
    __shared__ int rowc[64];

    // linear block id -> (bi, bj), bi <= bj
    int b = blockIdx.x;
    int r = 0, rem = b;
    while (rem >= (64 - r)) { rem -= (64 - r); r++; }
    int bi = r, bj = r + rem;
    int i0 = bi * 64, j0 = bj * 64;

    int tid = threadIdx.x;
    int li = tid & 63, kq = tid >> 6;   // loader mapping: row-in-tile, k-quad
    int tx = tid & 15, ty = tid >> 4;   // compute mapping

    float acc[4][4];
#pragma unroll
    for (int a = 0; a < 4; a++)
#pragma unroll
        for (int c = 0; c < 4; c++) acc[a][c] = 0.f;

    for (int k0 = 0; k0 < DD; k0 += BK) {
        float4 av = *(const float4*)&A[(size_t)(i0 + li) * DD + k0 + kq * 4];
        float4 bv = *(const float4*)&A[(size_t)(j0 + li) * DD + k0 + kq * 4];
        __syncthreads();   // previous iteration's reads done
        As[kq * 4 + 0][li] = av.x;
        As[kq * 4 + 1][li] = av.y;
        As[kq * 4 + 2][li] = av.z;
        As[kq * 4 + 3][li] = av.w;
        Bs[kq * 4 + 0][li] = bv.x;
        Bs[kq * 4 + 1][li] = bv.y;
        Bs[kq * 4 + 2][li] = bv.z;
        Bs[kq * 4 + 3][li] = bv.w;
        __syncthreads();
#pragma unroll
        for (int kk = 0; kk < BK; kk++) {
            float4 a4 = *(const float4*)&As[kk][ty * 4];
            float4 b4 = *(const float4*)&Bs[kk][tx * 4];
            float ar[4] = {a4.x, a4.y, a4.z, a4.w};
            float br[4] = {b4.x, b4.y, b4.z, b4.w};
#pragma unroll
            for (int a = 0; a < 4; a++)
#pragma unroll
                for (int c = 0; c < 4; c++) acc[a][c] += ar[a] * br[c];
        }
    }

    if (tid < 64) { colc[tid] = 0; rowc[tid] = 0; }
    __syncthreads();
#pragma unroll
    for (int c = 0; c < 4; c++) {
        int cc = 0;
#pragma unroll
        for (int a = 0; a < 4; a++) cc += (acc[a][c] >= 0.f) ? 1 : 0;
        atomicAdd(&colc[tx * 4 + c], cc);
    }
    if (bi != bj) {
#pragma unroll
        for (int a = 0; a < 4; a++) {
            int rc = 0;
#pragma unroll
            for (int c = 0; c < 4; c++) rc += (acc[a][c] >= 0.f) ? 1 : 0;
            atomicAdd(&rowc[ty * 4 + a], rc);
        }
    }
    __syncthreads();
    if (tid < 64) {
        atomicAdd(&counts[j0 + tid], colc[tid]);
        if (bi != bj) atomicAdd(&counts[i0 + tid], rowc[tid]);
    }
}

// ---------------- kernel 2: argmin(counts) -> blended seed ----------------
__global__ void k_seed(const int* __restrict__ counts, const int* __restrict__ attn_seed,
                       int* __restrict__ seedp) {
    __shared__ int bestC[256];
    __shared__ int bestI[256];
    int tid = threadIdx.x;
    int bc = 0x7fffffff, bI = 0;
    for (int j = tid; j < NP; j += 256) {
        int c = counts[j];
        if (c < bc) { bc = c; bI = j; }   // strict <: first occurrence within stride
    }
    bestC[tid] = bc; bestI[tid] = bI;
    __syncthreads();
    for (int st = 128; st > 0; st >>= 1) {
        if (tid < st) {
            if (bestC[tid + st] < bestC[tid] ||
                (bestC[tid + st] == bestC[tid] && bestI[tid + st] < bestI[tid])) {
                bestC[tid] = bestC[tid + st];
                bestI[tid] = bestI[tid + st];
            }
        }
        __syncthreads();
    }
    if (tid == 0) {
        int flat = bestI[0];
        int sr = flat / WD, sc = flat % WD;
        int vr = sr + attn_seed[0];   // 2*(0.5*sd + 0.5*as)
        int vc = sc + attn_seed[1];
        // jnp.round = round-half-to-even on x.5 values
        int rr, rc;
        if ((vr & 1) == 0) rr = vr >> 1;
        else { int m = vr >> 1; rr = (m & 1) ? m + 1 : m; }
        if ((vc & 1) == 0) rc = vc >> 1;
        else { int m = vc >> 1; rc = (m & 1) ? m + 1 : m; }
        seedp[0] = rr * WD + rc;
    }
}

// ---------------- kernel 3: sim[seed, :] row ----------------
__global__ __launch_bounds__(256) void k_simrow(const float* __restrict__ A,
                                                const int* __restrict__ seedp,
                                                float* __restrict__ simrow) {
    __shared__ float sv[DD];
    __shared__ float red[4];
    int seed = seedp[0];
    int tid = threadIdx.x;
    for (int k = tid; k < DD; k += 256) sv[k] = A[(size_t)seed * DD + k];
    __syncthreads();
    int jbase = blockIdx.x * 16;
    for (int jj = 0; jj < 16; jj++) {
        int j = jbase + jj;
        float p = 0.f;
        for (int k = tid; k < DD; k += 256) p += sv[k] * A[(size_t)j * DD + k];
        for (int o = 32; o > 0; o >>= 1) p += __shfl_down(p, o);
        if ((tid & 63) == 0) red[tid >> 6] = p;
        __syncthreads();
        if (tid == 0) simrow[j] = red[0] + red[1] + red[2] + red[3];
        __syncthreads();
    }
}

// ---------------- kernel 4: stable-argsort rank -> initial expansion set s ----------------
__global__ __launch_bounds__(256) void k_rank(const float* __restrict__ simrow,
                                              const int* __restrict__ seedp,
                                              int* __restrict__ s) {
    __shared__ float v[NP];   // 16 KB
    int tid = threadIdx.x;
    int j = blockIdx.x * 256 + tid;
    for (int k = tid; k < NP; k += 256) v[k] = simrow[k];
    __syncthreads();
    float mv = v[j];
    int rank = 0;
    for (int jp = 0; jp < NP; jp++) {
        float u = v[jp];
        // descending stable sort of sim: earlier = larger, ties broken by index
        rank += (u > mv || (u == mv && jp < j)) ? 1 : 0;
    }
    int seed = seedp[0];
    int sv = 0;
    if (rank < KTOP) sv = (mv >= 0.f || j == seed) ? 1 : 0;
    s[j] = sv;
}

// ---------------- kernel 5a: compact active indices (sorted ascending) ----------------
__global__ void k_compact(const int* __restrict__ s, int* __restrict__ act,
                          int* __restrict__ Mp) {
    __shared__ int pre[256];
    int tid = threadIdx.x;
    int c = 0;
    for (int n = 0; n < 16; n++) c += (s[tid * 16 + n] != 0) ? 1 : 0;
    pre[tid] = c;
    __syncthreads();
    if (tid == 0) {
        int run = 0;
        for (int i = 0; i < 256; i++) { int t = pre[i]; pre[i] = run; run += t; }
        Mp[0] = run;
    }
    __syncthreads();
    int off = pre[tid];
    for (int n = 0; n < 16; n++) {
        int idx = tid * 16 + n;
        if (s[idx] != 0) act[off++] = idx;
    }
}

// ---------------- kernel 5b: subsim[p][q] = dot(out[act_p], out[act_q]) ----------------
__global__ __launch_bounds__(128) void k_subsim(const float* __restrict__ A,
                                                const int* __restrict__ act,
                                                const int* __restrict__ Mp,
                                                float* __restrict__ subsim) {
    __shared__ float av[DD];
    int M = Mp[0];
    int p = blockIdx.x;
    if (p >= M) return;
    int tid = threadIdx.x;
    int ip = act[p];
    for (int k = tid; k < DD; k += 128) av[k] = A[(size_t)ip * DD + k];
    __syncthreads();
    if (tid < M) {
        int iq = act[tid];
        float sum = 0.f;
        for (int k = 0; k < DD; k++) sum += av[k] * A[(size_t)iq * DD + k];
        subsim[p * 128 + tid] = sum;
    }
}

// ---------------- kernel 5c: sequential expansion scan (one wave) ----------------
__global__ void k_expand(const float* __restrict__ subsim, const int* __restrict__ act,
                         const int* __restrict__ Mp, int* __restrict__ s) {
    int M = Mp[0];
    int lane = threadIdx.x;   // 64 lanes
    float alive_lo = (lane < M) ? 1.f : 0.f;        // all active start at s==1
    float alive_hi = (lane + 64 < M) ? 1.f : 0.f;
    for (int p = 0; p < M; p++) {
        float part = 0.f;
        if (lane < M)      part += subsim[p * 128 + lane] * alive_lo;
        if (lane + 64 < M) part += subsim[p * 128 + lane + 64] * alive_hi;
        for (int o = 1; o < 64; o <<= 1) part += __shfl_xor(part, o);
        if (!(part > 0.f)) {
            if (lane == p)      alive_lo = 0.f;
            if (lane + 64 == p) alive_hi = 0.f;
            if (lane == 0) s[act[p]] = 0;
        }
    }
}

// ---------------- kernel 6: 8-connected CC, min-label propagation ----------------
__global__ __launch_bounds__(256) void k_cc(const int* __restrict__ s, int* __restrict__ outp) {
    __shared__ int lab[NP];   // 16 KB
    __shared__ int chg;
    int tid = threadIdx.x;
    for (int n = tid; n < NP; n += 256) lab[n] = (s[n] != 0) ? (n + 1) : BIGL;
    __syncthreads();
    while (true) {
        if (tid == 0) chg = 0;
        __syncthreads();
        int local = 0;
        for (int n = tid; n < NP; n += 256) {
            int v = lab[n];
            if (v == BIGL) continue;   // background never updates
            int y = n >> 6, x = n & 63;
            int m = v;
#pragma unroll
            for (int dy = -1; dy <= 1; dy++)
#pragma unroll
                for (int dx = -1; dx <= 1; dx++) {
                    int yy = y + dy, xx = x + dx;
                    if (yy < 0 || yy >= HD || xx < 0 || xx >= WD) continue;
                    int u = lab[(yy << 6) + xx];
                    if (u < m) m = u;
                }
            if (m < v) { lab[n] = m; local = 1; }   // monotone: Gauss-Seidel safe
        }
        if (local) chg = 1;
        __syncthreads();
        if (chg == 0) break;
        __syncthreads();   // protect chg read before next reset
    }
    for (int n = tid; n < NP; n += 256) outp[n] = (lab[n] == BIGL) ? 0 : lab[n];
}

extern "C" void kernel_launch(void* const* d_in, const int* in_sizes, int n_in,
                              void* d_out, int out_size, void* d_ws, size_t ws_size,
                              hipStream_t stream) {
    const float* A = (const float*)d_in[0];       // out: (4096, 768) fp32
    const int* attn = (const int*)d_in[1];        // attn_seed: (2,) int32
    int* outp = (int*)d_out;                      // labels: (64,64) int32

    char* ws = (char*)d_ws;
    int*   counts = (int*)(ws);                   // 4096 ints
    float* simrow = (float*)(ws + 16384);         // 4096 floats
    int*   s      = (int*)(ws + 32768);           // 4096 ints
    int*   act    = (int*)(ws + 49152);           // 128 ints
    int*   Mp     = (int*)(ws + 49152 + 512);
    int*   seedp  = (int*)(ws + 49152 + 516);
    float* subsim = (float*)(ws + 50176);         // 128*128 floats

    k_zero   <<<16,   256, 0, stream>>>(counts, NP);
    k_count  <<<2080, 256, 0, stream>>>(A, counts);
    k_seed   <<<1,    256, 0, stream>>>(counts, attn, seedp);
    k_simrow <<<256,  256, 0, stream>>>(A, seedp, simrow);
    k_rank   <<<16,   256, 0, stream>>>(simrow, seedp, s);
    k_compact<<<1,    256, 0, stream>>>(s, act, Mp);
    k_subsim <<<128,  128, 0, stream>>>(A, act, Mp, subsim);
    k_expand <<<1,    64,  0, stream>>>(subsim, act, Mp, s);
    k_cc     <<<1,    256, 0, stream>>>(s, outp);
}